// Round 1
// baseline (1601.431 us; speedup 1.0000x reference)
//
#include <hip/hip_runtime.h>

// DeformConv3D forward, fp32. B=2, C=Cout=64, D=8, H=56, W=56, K=27,
// stride=pad=dil=1, deform_groups=1, groups=1.
#define CIN  64
#define COUT 64
#define DD   8
#define HH   56
#define WWID 56
#define KK   27
#define PP   (DD * HH * WWID)   // 25088
#define BB   2

// Transpose weight [co][c][k] -> wT[k][c][co] so the GEMM inner loop can do
// float4 loads along co (uniform across lanes -> L1 broadcast).
__global__ __launch_bounds__(256) void transpose_w_kernel(
    const float* __restrict__ w, float* __restrict__ wT)
{
    int idx = blockIdx.x * 256 + threadIdx.x;
    if (idx >= COUT * CIN * KK) return;
    int k  = idx % KK;
    int t  = idx / KK;
    int c  = t % CIN;
    int co = t / CIN;
    wT[(k * CIN + c) * COUT + co] = w[idx];
}

// Thread = (output voxel, half of co). acc[32] fp32. 784 blocks x 128 thr.
template <bool USE_WT>
__global__ __launch_bounds__(128) void deform_conv3d_kernel(
    const float* __restrict__ x, const float* __restrict__ off,
    const float* __restrict__ wsrc, float* __restrict__ out)
{
    const int co_half = blockIdx.x / 392;                       // 0 or 1
    const int vox     = (blockIdx.x % 392) * 128 + threadIdx.x; // 0..50175
    const int b  = vox / PP;
    const int p  = vox - b * PP;
    const int wq = p % WWID;
    const int hq = (p / WWID) % HH;
    const int dq = p / (HH * WWID);
    const int co_base = co_half * 32;

    const float* xb   = x + b * (CIN * PP);
    const float* offb = off + b * (3 * KK * PP) + p;

    float acc[32];
#pragma unroll
    for (int j = 0; j < 32; ++j) acc[j] = 0.f;

    for (int k = 0; k < KK; ++k) {
        const int kd = k / 9, kh = (k / 3) % 3, kw = k % 3;
        // offsets for this tap (coalesced across lanes: consecutive p)
        const float od = offb[(k * 3 + 0) * PP];
        const float oh = offb[(k * 3 + 1) * PP];
        const float ow = offb[(k * 3 + 2) * PP];
        const float pd = od + (float)(dq - 1 + kd);
        const float ph = oh + (float)(hq - 1 + kh);
        const float pw = ow + (float)(wq - 1 + kw);
        const float d0f = floorf(pd), h0f = floorf(ph), w0f = floorf(pw);
        const float fd = pd - d0f, fh = ph - h0f, fw = pw - w0f;
        const int d0 = (int)d0f, h0 = (int)h0f, w0 = (int)w0f;
        const int d1 = d0 + 1, h1 = h0 + 1, w1 = w0 + 1;

        // per-corner validity folded into weights; clamped indices keep loads safe
        const float wd0 = (1.f - fd) * ((d0 >= 0 && d0 < DD) ? 1.f : 0.f);
        const float wd1 = fd        * ((d1 >= 0 && d1 < DD) ? 1.f : 0.f);
        const float wh0 = (1.f - fh) * ((h0 >= 0 && h0 < HH) ? 1.f : 0.f);
        const float wh1 = fh        * ((h1 >= 0 && h1 < HH) ? 1.f : 0.f);
        const float ww0 = (1.f - fw) * ((w0 >= 0 && w0 < WWID) ? 1.f : 0.f);
        const float ww1 = fw        * ((w1 >= 0 && w1 < WWID) ? 1.f : 0.f);

        const int cd0 = min(max(d0, 0), DD - 1),  cd1 = min(max(d1, 0), DD - 1);
        const int ch0 = min(max(h0, 0), HH - 1),  ch1 = min(max(h1, 0), HH - 1);
        const int cw0 = min(max(w0, 0), WWID - 1), cw1 = min(max(w1, 0), WWID - 1);

        const int l000 = (cd0 * HH + ch0) * WWID + cw0;
        const int l001 = (cd0 * HH + ch0) * WWID + cw1;
        const int l010 = (cd0 * HH + ch1) * WWID + cw0;
        const int l011 = (cd0 * HH + ch1) * WWID + cw1;
        const int l100 = (cd1 * HH + ch0) * WWID + cw0;
        const int l101 = (cd1 * HH + ch0) * WWID + cw1;
        const int l110 = (cd1 * HH + ch1) * WWID + cw0;
        const int l111 = (cd1 * HH + ch1) * WWID + cw1;

        const float c000 = wd0 * wh0 * ww0;
        const float c001 = wd0 * wh0 * ww1;
        const float c010 = wd0 * wh1 * ww0;
        const float c011 = wd0 * wh1 * ww1;
        const float c100 = wd1 * wh0 * ww0;
        const float c101 = wd1 * wh0 * ww1;
        const float c110 = wd1 * wh1 * ww0;
        const float c111 = wd1 * wh1 * ww1;

        for (int c = 0; c < CIN; ++c) {
            const float* xc = xb + c * PP;
            float v = c000 * xc[l000] + c001 * xc[l001]
                    + c010 * xc[l010] + c011 * xc[l011]
                    + c100 * xc[l100] + c101 * xc[l101]
                    + c110 * xc[l110] + c111 * xc[l111];

            if (USE_WT) {
                const float* wp = wsrc + (k * CIN + c) * COUT + co_base;
#pragma unroll
                for (int j = 0; j < 32; j += 4) {
                    const float4 w4 = *(const float4*)(wp + j);
                    acc[j + 0] += w4.x * v;
                    acc[j + 1] += w4.y * v;
                    acc[j + 2] += w4.z * v;
                    acc[j + 3] += w4.w * v;
                }
            } else {
#pragma unroll
                for (int j = 0; j < 32; ++j) {
                    acc[j] += wsrc[((co_base + j) * CIN + c) * KK + k] * v;
                }
            }
        }
    }

    float* ob = out + b * (COUT * PP) + co_base * PP + p;
#pragma unroll
    for (int j = 0; j < 32; ++j) ob[j * PP] = acc[j];
}

extern "C" void kernel_launch(void* const* d_in, const int* in_sizes, int n_in,
                              void* d_out, int out_size, void* d_ws, size_t ws_size,
                              hipStream_t stream)
{
    const float* x   = (const float*)d_in[0];
    const float* off = (const float*)d_in[1];
    const float* w   = (const float*)d_in[2];
    float* out = (float*)d_out;

    const size_t wt_bytes = (size_t)KK * CIN * COUT * sizeof(float); // 442368
    const int nblk = 2 * 392; // co halves x voxel tiles

    if (ws_size >= wt_bytes) {
        float* wT = (float*)d_ws;
        const int nw = COUT * CIN * KK;
        transpose_w_kernel<<<(nw + 255) / 256, 256, 0, stream>>>(w, wT);
        deform_conv3d_kernel<true><<<nblk, 128, 0, stream>>>(x, off, wT, out);
    } else {
        deform_conv3d_kernel<false><<<nblk, 128, 0, stream>>>(x, off, w, out);
    }
}